// Round 3
// baseline (376.421 us; speedup 1.0000x reference)
//
#include <hip/hip_runtime.h>
#include <hip/hip_bf16.h>
#include <math.h>

#define NROWS 2048
#define DIN 256
#define DH 32
#define DOUT 256

typedef unsigned short ushort_t;
typedef unsigned int uint_t;
typedef __attribute__((ext_vector_type(8))) short short8;
typedef __attribute__((ext_vector_type(4))) float floatx4;
typedef __attribute__((ext_vector_type(4))) ushort_t ushortx4;

__device__ __forceinline__ float bf2f(uint_t u) {
    union { uint_t i; float f; } v; v.i = u << 16; return v.f;
}
__device__ __forceinline__ ushort_t f2bf(float f) {
    __hip_bfloat16 h = __float2bfloat16(f);
    union { __hip_bfloat16 h; ushort_t u; } v; v.h = h; return v.u;
}
__device__ __forceinline__ float sigm(float v) { return 1.0f / (1.0f + __expf(-v)); }

// LDS strides in shorts; byte strides are 16-B multiples.
#define PSTR 2056   // 16 rows x 2056 shorts = 65792 B (P, bf16)
#define ASTR 520    // 16 rows x 520 shorts  = 16640 B ([x|agg], bf16)

// ---------------- Kernel 1: MLPs + B-fragment packing ----------------
// grid 592 x 256:
//   b <  256 : x MLP     -> x_attB (bf16 row-major, A-frag friendly)
//   b <  512 : neibs MLP -> n_attP (bf16, MFMA-B fragment order for scores)
//   b <  576 : neibs     -> B_pack (bf16 B-frag order, LDS-transposed, 1 MB)
//   b <  592 : fcx_w     -> W_pack (bf16 B-frag order, 256 KB)
// B-frag order (16x16x32): group g = s*1024 + ct*64 + q*16 + n holds
// B[k=32s+8q+j][col=16ct+n], j=0..7: col-tile ct (0..15) within slab s is one
// contiguous 1 KB slab with lane-contiguous 16-B loads.
__global__ __launch_bounds__(256) void prep_kernel(
    const float* __restrict__ x, const float* __restrict__ neibs,
    const float* __restrict__ ax_w1, const float* __restrict__ ax_b1,
    const float* __restrict__ ax_w2, const float* __restrict__ ax_b2,
    const float* __restrict__ an_w1, const float* __restrict__ an_b1,
    const float* __restrict__ an_w2, const float* __restrict__ an_b2,
    const float* __restrict__ fcx_w,
    ushort_t* __restrict__ x_attB, short8* __restrict__ n_attP,
    short8* __restrict__ B_pack, short8* __restrict__ W_pack)
{
    __shared__ float smem[32 * 256];   // 32 KB, reused per branch
    const int t = threadIdx.x;
    const int b = blockIdx.x;

    if (b < 512) {
        float (*srow)[DIN] = (float (*)[DIN])smem;      // 8x256
        float* hbuf = smem + 8 * DIN;                   // 8x32
        float* sbuf = smem + 8 * DIN + 8 * DH;          // 8x32

        const bool is_x = b < 256;
        const int row0 = (is_x ? b : b - 256) * 8;
        const float* __restrict__ in = is_x ? x : neibs;
        const float* __restrict__ w1 = is_x ? ax_w1 : an_w1;
        const float* __restrict__ b1 = is_x ? ax_b1 : an_b1;
        const float* __restrict__ w2 = is_x ? ax_w2 : an_w2;
        const float* __restrict__ b2 = is_x ? ax_b2 : an_b2;

        const int r = t >> 5, c = t & 31;
        {
            const float4* in4 = (const float4*)(in + (size_t)(row0 + r) * DIN);
            float4 a = in4[c * 2], bb = in4[c * 2 + 1];
            *(float4*)&srow[r][c * 8] = a;
            *(float4*)&srow[r][c * 8 + 4] = bb;
        }
        __syncthreads();

        float s = b1[c];
#pragma unroll 8
        for (int k = 0; k < DIN; ++k) s += srow[r][k] * w1[k * DH + c];
        s = tanhf(s);
        hbuf[r * DH + c] = s;
        __syncthreads();

        float s2 = b2[c];
#pragma unroll
        for (int j = 0; j < DH; ++j) s2 += hbuf[r * DH + j] * w2[j * DH + c];

        if (is_x) {
            x_attB[(size_t)(row0 + r) * DH + c] = f2bf(s2);
        } else {
            sbuf[r * DH + c] = s2;
            __syncthreads();
            if (t < 32) {
                const int r2 = t >> 2, q = t & 3;
                const int row = row0 + r2;
                short8 v;
#pragma unroll
                for (int j = 0; j < 8; ++j) v[j] = (short)f2bf(sbuf[r2 * DH + q * 8 + j]);
                n_attP[(row >> 4) * 64 + q * 16 + (row & 15)] = v;
            }
        }
    } else if (b < 576) {
        // B_pack: slab s of 32 k-rows x 256 cols, LDS transpose.
        const int s = b - 512;                           // 0..63
        float* tile = smem;                              // [32][256]
#pragma unroll
        for (int i = 0; i < 8; ++i) {
            const int e = i * 256 + t;                   // float4 index
            const int row = e >> 6, c4 = e & 63;
            const float4 v = ((const float4*)neibs)[(size_t)(32 * s + row) * 64 + c4];
            *(float4*)&tile[row * 256 + c4 * 4] = v;
        }
        __syncthreads();
#pragma unroll
        for (int i = 0; i < 4; ++i) {
            const int G = i * 256 + t;                   // 0..1023
            const int n = G & 15, q = (G >> 4) & 3, ct = G >> 6;
            const int col = ct * 16 + n;
            short8 v;
#pragma unroll
            for (int j = 0; j < 8; ++j) v[j] = (short)f2bf(tile[(8 * q + j) * 256 + col]);
            B_pack[s * 1024 + G] = v;
        }
    } else {
        // W_pack: same, source fcx_w (512x256), 16 slabs.
        const int s = b - 576;                           // 0..15
        float* tile = smem;
#pragma unroll
        for (int i = 0; i < 8; ++i) {
            const int e = i * 256 + t;
            const int row = e >> 6, c4 = e & 63;
            const float4 v = ((const float4*)fcx_w)[(size_t)(32 * s + row) * 64 + c4];
            *(float4*)&tile[row * 256 + c4 * 4] = v;
        }
        __syncthreads();
#pragma unroll
        for (int i = 0; i < 4; ++i) {
            const int G = i * 256 + t;
            const int n = G & 15, q = (G >> 4) & 3, ct = G >> 6;
            const int col = ct * 16 + n;
            short8 v;
#pragma unroll
            for (int j = 0; j < 8; ++j) v[j] = (short)f2bf(tile[(8 * q + j) * 256 + col]);
            W_pack[s * 1024 + G] = v;
        }
    }
}

// ---------------- Kernel 2: MFMA scores + softmax + MFMA PV + MFMA FC ----
// v3: 128 blocks x 512 threads (8 waves); block = 16 target rows.
//  * 16x16 MFMA tiles now carry 16 DISTINCT rows (v2 wasted half of every
//    phase-1 MFMA on duplicated rows 8-15).
//  * B_pack L2 traffic halves (128 blocks x 1 MB = 128 MB, was 256 MB);
//    W_pack likewise (32 MB, was 64 MB). Phase 2 was L2-BW-bound.
//  * Epilogues: each lane writes its 4 C-regs to 4 distinct rows
//    (crow0 = (lane>>4)*4) -- no duplication tricks needed.
//  * Softmax: wave w owns rows 2w, 2w+1 sequentially.
//  * Still 3 barriers, full-K per-wave accumulators (no LDS reduce).
__global__ __launch_bounds__(512, 2) void attn_kernel(
    const float* __restrict__ x, const float* __restrict__ mask,
    const ushort_t* __restrict__ x_attB, const short8* __restrict__ n_attP,
    const short8* __restrict__ B_pack, const short8* __restrict__ W_pack,
    const float* __restrict__ fcx_b, float* __restrict__ out)
{
    __shared__ __align__(16) ushort_t pTr[16 * PSTR];   // 65.8 KB
    __shared__ __align__(16) ushort_t ATr[16 * ASTR];   // 16.6 KB
    __shared__ float row_inv[16];

    const int t = threadIdx.x;
    const int n0 = blockIdx.x * 16;
    const int w = t >> 6, lane = t & 63;
    const int q = lane >> 4, nn = lane & 15;
    const int arow = lane & 15;                // A-frag row: 16 distinct rows
    const int crow0 = (lane >> 4) * 4;         // C rows crow0..crow0+3 (regs 0..3)

    // ---- Phase 0: stage x rows into ATr cols 0..255 (bf16), vectorized ----
#pragma unroll
    for (int i = 0; i < 2; ++i) {
        const int e = i * 512 + t;                      // 16 rows x 64 float4
        const int r = e >> 6, c4 = e & 63;
        const float4 v = *(const float4*)(x + (size_t)(n0 + r) * DIN + c4 * 4);
        ushortx4 o;
        o.x = f2bf(v.x); o.y = f2bf(v.y); o.z = f2bf(v.z); o.w = f2bf(v.w);
        *(ushortx4*)&ATr[r * ASTR + c4 * 4] = o;
    }

    // ---- Phase 1: scores via MFMA (K=32, one MFMA per 16-col tile) ----
    const short8 av_s = *(const short8*)(x_attB + (size_t)(n0 + arow) * DH + q * 8);
#pragma unroll 4
    for (int i = 0; i < 16; ++i) {
        const int tl = w * 16 + i;
        const short8 bv = n_attP[tl * 64 + lane];
        floatx4 c = __builtin_amdgcn_mfma_f32_16x16x32_bf16(
            av_s, bv, (floatx4){0.f, 0.f, 0.f, 0.f}, 0, 0, 0);
        const int m = tl * 16 + nn;
#pragma unroll
        for (int rg = 0; rg < 4; ++rg) {
            const int row = crow0 + rg;
            const float sv = c[rg] * mask[(size_t)(n0 + row) * NROWS + m];
            pTr[row * PSTR + m] = f2bf(sv);
        }
    }
    __syncthreads();                               // barrier #1

    // ---- Phase 1b: softmax; wave w -> rows 2w, 2w+1. b32 LDS ops ----
#pragma unroll
    for (int rr = 0; rr < 2; ++rr) {
        const int row = 2 * w + rr;
        ushort_t* prow = pTr + row * PSTR;
        uint_t raw[16];
        float mx = -1e30f;
#pragma unroll
        for (int j = 0; j < 16; ++j) {
            raw[j] = *(const uint_t*)(prow + j * 128 + 2 * lane);
            mx = fmaxf(mx, fmaxf(bf2f(raw[j] & 0xffffu), bf2f(raw[j] >> 16)));
        }
#pragma unroll
        for (int off = 32; off >= 1; off >>= 1) mx = fmaxf(mx, __shfl_xor(mx, off));
        float sum = 0.f;
#pragma unroll
        for (int j = 0; j < 16; ++j) {
            const float e0 = __expf(bf2f(raw[j] & 0xffffu) - mx);
            const float e1 = __expf(bf2f(raw[j] >> 16) - mx);
            sum += e0 + e1;
            *(uint_t*)(prow + j * 128 + 2 * lane) =
                (uint_t)f2bf(e0) | ((uint_t)f2bf(e1) << 16);
        }
#pragma unroll
        for (int off = 32; off >= 1; off >>= 1) sum += __shfl_xor(sum, off);
        if (lane == 0) row_inv[row] = 1.f / sum;
    }
    __syncthreads();                               // barrier #2

    // ---- Phase 2: PV. wave w: col tiles 2w, 2w+1; FULL K (64 slabs) ----
    const char* aBase = (const char*)pTr + arow * (PSTR * 2);
    floatx4 accP[2][2];
#pragma unroll
    for (int tt = 0; tt < 2; ++tt)
#pragma unroll
        for (int pr = 0; pr < 2; ++pr) accP[tt][pr] = (floatx4){0.f, 0.f, 0.f, 0.f};

#pragma unroll 4
    for (int s = 0; s < 64; ++s) {
        const short8 av = *(const short8*)(aBase + s * 64 + q * 16);
        const int pr = s & 1;
#pragma unroll
        for (int tt = 0; tt < 2; ++tt) {
            const short8 bv = B_pack[(s * 16 + 2 * w + tt) * 64 + lane];
            accP[tt][pr] = __builtin_amdgcn_mfma_f32_16x16x32_bf16(av, bv, accP[tt][pr], 0, 0, 0);
        }
    }
    // epilogue: sigmoid(acc * row_inv) -> ATr cols 256..511, 4 rows per lane
#pragma unroll
    for (int tt = 0; tt < 2; ++tt) {
        const floatx4 a = accP[tt][0] + accP[tt][1];
        const int n = w * 32 + tt * 16 + nn;
#pragma unroll
        for (int rg = 0; rg < 4; ++rg) {
            const int row = crow0 + rg;
            ATr[row * ASTR + 256 + n] = f2bf(sigm(a[rg] * row_inv[row]));
        }
    }
    __syncthreads();                               // barrier #3

    // ---- Phase 3: FC. K=512 (16 slabs), wave w: col tiles 2w, 2w+1 ----
    const char* a2 = (const char*)ATr + arow * (ASTR * 2);
    floatx4 acc2[2][2];
#pragma unroll
    for (int tt = 0; tt < 2; ++tt)
#pragma unroll
        for (int pr = 0; pr < 2; ++pr) acc2[tt][pr] = (floatx4){0.f, 0.f, 0.f, 0.f};

#pragma unroll
    for (int s = 0; s < 16; ++s) {
        const short8 av = *(const short8*)(a2 + s * 64 + q * 16);
        const int pr = s & 1;
#pragma unroll
        for (int tt = 0; tt < 2; ++tt) {
            const short8 bv = W_pack[(s * 16 + 2 * w + tt) * 64 + lane];
            acc2[tt][pr] = __builtin_amdgcn_mfma_f32_16x16x32_bf16(av, bv, acc2[tt][pr], 0, 0, 0);
        }
    }
#pragma unroll
    for (int tt = 0; tt < 2; ++tt) {
        const floatx4 a = acc2[tt][0] + acc2[tt][1];
        const int n = w * 32 + tt * 16 + nn;
        const float bias = fcx_b[n];
#pragma unroll
        for (int rg = 0; rg < 4; ++rg) {
            const int row = crow0 + rg;
            out[(size_t)(n0 + row) * DOUT + n] = sigm(a[rg] + bias);
        }
    }
}

extern "C" void kernel_launch(void* const* d_in, const int* in_sizes, int n_in,
                              void* d_out, int out_size, void* d_ws, size_t ws_size,
                              hipStream_t stream) {
    const float* x      = (const float*)d_in[0];
    const float* neibs  = (const float*)d_in[1];
    // d_in[2] = edge_emb: dead code in the reference, intentionally unread.
    const float* mask   = (const float*)d_in[3];
    const float* ax_w1  = (const float*)d_in[4];
    const float* ax_b1  = (const float*)d_in[5];
    const float* ax_w2  = (const float*)d_in[6];
    const float* ax_b2  = (const float*)d_in[7];
    const float* an_w1  = (const float*)d_in[8];
    const float* an_b1  = (const float*)d_in[9];
    const float* an_w2  = (const float*)d_in[10];
    const float* an_b2  = (const float*)d_in[11];
    // d_in[12..15] = ae_* : dead code, unread.
    const float* fcx_w  = (const float*)d_in[16];
    const float* fcx_b  = (const float*)d_in[17];
    float* out = (float*)d_out;

    char* ws = (char*)d_ws;
    ushort_t* x_attB = (ushort_t*)ws;                    // 128 KB
    short8*   n_attP = (short8*)(ws + 131072);           // 128 KB
    short8*   B_pack = (short8*)(ws + 262144);           // 1 MB
    short8*   W_pack = (short8*)(ws + 1310720);          // 256 KB

    prep_kernel<<<592, 256, 0, stream>>>(
        x, neibs, ax_w1, ax_b1, ax_w2, ax_b2,
        an_w1, an_b1, an_w2, an_b2, fcx_w,
        x_attB, n_attP, B_pack, W_pack);

    attn_kernel<<<128, 512, 0, stream>>>(
        x, mask, x_attB, n_attP, B_pack, W_pack, fcx_b, out);
}

// Round 4
// 363.593 us; speedup vs baseline: 1.0353x; 1.0353x over previous
//
#include <hip/hip_runtime.h>
#include <hip/hip_bf16.h>
#include <math.h>

#define NROWS 2048
#define DIN 256
#define DH 32
#define DOUT 256

typedef unsigned short ushort_t;
typedef unsigned int uint_t;
typedef unsigned char uchar_t;
typedef long long i64;
typedef __attribute__((ext_vector_type(8))) short short8;
typedef __attribute__((ext_vector_type(4))) float floatx4;
typedef __attribute__((ext_vector_type(4))) ushort_t ushortx4;

__device__ __forceinline__ float bf2f(uint_t u) {
    union { uint_t i; float f; } v; v.i = u << 16; return v.f;
}
__device__ __forceinline__ ushort_t f2bf(float f) {
    __hip_bfloat16 h = __float2bfloat16(f);
    union { __hip_bfloat16 h; ushort_t u; } v; v.h = h; return v.u;
}
__device__ __forceinline__ float sigm(float v) { return 1.0f / (1.0f + __expf(-v)); }

// LDS strides.
#define PSTR 2056     // bf16 score rows: 8 x 2056 shorts = 32896 B
#define PF8STR 2064   // fp8 P rows: 8 x 2064 B = 16512 B (stride%8==0, row shift
                      //  = 516 dwords = 4 banks -> conflict-free b64 A-frag reads)
#define ASTR 520      // [x|agg] bf16 rows: 8 x 520 shorts = 8320 B

// ---------------- Kernel 1: MLPs + B-fragment packing ----------------
// grid 592 x 256:
//   b <  256 : x MLP     -> x_attB (bf16 row-major, A-frag friendly)
//   b <  512 : neibs MLP -> n_attP (bf16, MFMA-B fragment order for scores)
//   b <  576 : neibs     -> B_pack8 (fp8 e4m3 B-frag order, 512 KB)
//   b <  592 : fcx_w     -> W_pack (bf16 B-frag order, 256 KB)
// bf16 B-frag (16x16x32): group g = s*1024 + ct*64 + q*16 + n holds
// B[k=32s+8q+j][col=16ct+n], j=0..7. fp8 B-frag uses the IDENTICAL index
// mapping (8 values/lane), just 8 B per lane instead of 16.
__global__ __launch_bounds__(256) void prep_kernel(
    const float* __restrict__ x, const float* __restrict__ neibs,
    const float* __restrict__ ax_w1, const float* __restrict__ ax_b1,
    const float* __restrict__ ax_w2, const float* __restrict__ ax_b2,
    const float* __restrict__ an_w1, const float* __restrict__ an_b1,
    const float* __restrict__ an_w2, const float* __restrict__ an_b2,
    const float* __restrict__ fcx_w,
    ushort_t* __restrict__ x_attB, short8* __restrict__ n_attP,
    i64* __restrict__ B_pack8, short8* __restrict__ W_pack)
{
    __shared__ float smem[32 * 256];   // 32 KB, reused per branch
    const int t = threadIdx.x;
    const int b = blockIdx.x;

    if (b < 512) {
        float (*srow)[DIN] = (float (*)[DIN])smem;      // 8x256
        float* hbuf = smem + 8 * DIN;                   // 8x32
        float* sbuf = smem + 8 * DIN + 8 * DH;          // 8x32

        const bool is_x = b < 256;
        const int row0 = (is_x ? b : b - 256) * 8;
        const float* __restrict__ in = is_x ? x : neibs;
        const float* __restrict__ w1 = is_x ? ax_w1 : an_w1;
        const float* __restrict__ b1 = is_x ? ax_b1 : an_b1;
        const float* __restrict__ w2 = is_x ? ax_w2 : an_w2;
        const float* __restrict__ b2 = is_x ? ax_b2 : an_b2;

        const int r = t >> 5, c = t & 31;
        {
            const float4* in4 = (const float4*)(in + (size_t)(row0 + r) * DIN);
            float4 a = in4[c * 2], bb = in4[c * 2 + 1];
            *(float4*)&srow[r][c * 8] = a;
            *(float4*)&srow[r][c * 8 + 4] = bb;
        }
        __syncthreads();

        float s = b1[c];
#pragma unroll 8
        for (int k = 0; k < DIN; ++k) s += srow[r][k] * w1[k * DH + c];
        s = tanhf(s);
        hbuf[r * DH + c] = s;
        __syncthreads();

        float s2 = b2[c];
#pragma unroll
        for (int j = 0; j < DH; ++j) s2 += hbuf[r * DH + j] * w2[j * DH + c];

        if (is_x) {
            x_attB[(size_t)(row0 + r) * DH + c] = f2bf(s2);
        } else {
            sbuf[r * DH + c] = s2;
            __syncthreads();
            if (t < 32) {
                const int r2 = t >> 2, q = t & 3;
                const int row = row0 + r2;
                short8 v;
#pragma unroll
                for (int j = 0; j < 8; ++j) v[j] = (short)f2bf(sbuf[r2 * DH + q * 8 + j]);
                n_attP[(row >> 4) * 64 + q * 16 + (row & 15)] = v;
            }
        }
    } else if (b < 576) {
        // B_pack8: slab s of 32 k-rows x 256 cols, LDS transpose, fp8 e4m3.
        const int s = b - 512;                           // 0..63
        float* tile = smem;                              // [32][256]
#pragma unroll
        for (int i = 0; i < 8; ++i) {
            const int e = i * 256 + t;                   // float4 index
            const int row = e >> 6, c4 = e & 63;
            const float4 v = ((const float4*)neibs)[(size_t)(32 * s + row) * 64 + c4];
            *(float4*)&tile[row * 256 + c4 * 4] = v;
        }
        __syncthreads();
#pragma unroll
        for (int i = 0; i < 4; ++i) {
            const int G = i * 256 + t;                   // 0..1023
            const int n = G & 15, q = (G >> 4) & 3, ct = G >> 6;
            const int col = ct * 16 + n;
            int lo = 0, hi = 0;
            lo = __builtin_amdgcn_cvt_pk_fp8_f32(
                tile[(8 * q + 0) * 256 + col], tile[(8 * q + 1) * 256 + col], lo, false);
            lo = __builtin_amdgcn_cvt_pk_fp8_f32(
                tile[(8 * q + 2) * 256 + col], tile[(8 * q + 3) * 256 + col], lo, true);
            hi = __builtin_amdgcn_cvt_pk_fp8_f32(
                tile[(8 * q + 4) * 256 + col], tile[(8 * q + 5) * 256 + col], hi, false);
            hi = __builtin_amdgcn_cvt_pk_fp8_f32(
                tile[(8 * q + 6) * 256 + col], tile[(8 * q + 7) * 256 + col], hi, true);
            B_pack8[s * 1024 + G] =
                (i64)(((unsigned long long)(uint_t)hi << 32) | (uint_t)lo);
        }
    } else {
        // W_pack: bf16, source fcx_w (512x256), 16 slabs.
        const int s = b - 576;                           // 0..15
        float* tile = smem;
#pragma unroll
        for (int i = 0; i < 8; ++i) {
            const int e = i * 256 + t;
            const int row = e >> 6, c4 = e & 63;
            const float4 v = ((const float4*)fcx_w)[(size_t)(32 * s + row) * 64 + c4];
            *(float4*)&tile[row * 256 + c4 * 4] = v;
        }
        __syncthreads();
#pragma unroll
        for (int i = 0; i < 4; ++i) {
            const int G = i * 256 + t;
            const int n = G & 15, q = (G >> 4) & 3, ct = G >> 6;
            const int col = ct * 16 + n;
            short8 v;
#pragma unroll
            for (int j = 0; j < 8; ++j) v[j] = (short)f2bf(tile[(8 * q + j) * 256 + col]);
            W_pack[s * 1024 + G] = v;
        }
    }
}

// ---------------- Kernel 2: MFMA scores + softmax + MFMA PV(fp8) + MFMA FC ----
// v4 = v2 geometry (256 blocks x 512 thr, 8 rows/block, 3 barriers, full-K
// per-wave accumulators) + fp8 PV:
//  * softmax writes exp values as fp8 e4m3 into pF8 (lane-linear b32 writes);
//  * PV uses mfma_f32_16x16x32_fp8_fp8: A = 8B/lane from pF8 (ds_read_b64,
//    conflict-free via PF8STR=2064), B = 8B/lane from 512 KB B_pack8
//    -> halves the dominant per-CU L2 term (1 MB -> 512 KB per block).
//  * scores + softmax stats + FC remain bf16/f32 (accuracy).
__global__ __launch_bounds__(512, 2) void attn_kernel(
    const float* __restrict__ x, const float* __restrict__ mask,
    const ushort_t* __restrict__ x_attB, const short8* __restrict__ n_attP,
    const i64* __restrict__ B_pack8, const short8* __restrict__ W_pack,
    const float* __restrict__ fcx_b, float* __restrict__ out)
{
    __shared__ __align__(16) ushort_t pTr[8 * PSTR];    // 32.9 KB bf16 scores
    __shared__ __align__(16) uchar_t pF8[8 * PF8STR];   // 16.5 KB fp8 exp(P)
    __shared__ __align__(16) ushort_t ATr[8 * ASTR];    // 8.3 KB [x|agg] bf16
    __shared__ float row_inv[8];

    const int t = threadIdx.x;
    const int n0 = blockIdx.x * 8;
    const int w = t >> 6, lane = t & 63;
    const int q = lane >> 4, nn = lane & 15;
    const int arow = lane & 7;                 // A row (tile rows 8-15 dup 0-7)
    const int gl = lane >> 4;                  // C lane-group 0..3
    const int prow0 = (gl & 1) * 4 + (gl >> 1) * 2;   // first row this group writes
    const int reg0 = (gl >> 1) * 2;                    // first C reg this group uses

    // ---- Phase 0: stage x rows into ATr cols 0..255 (bf16), vectorized ----
    {
        const int r = t >> 6, c4 = t & 63;             // 8 rows x 64 float4
        const float4 v = *(const float4*)(x + (size_t)(n0 + r) * DIN + c4 * 4);
        ushortx4 o;
        o.x = f2bf(v.x); o.y = f2bf(v.y); o.z = f2bf(v.z); o.w = f2bf(v.w);
        *(ushortx4*)&ATr[r * ASTR + c4 * 4] = o;
    }

    // ---- Phase 1: scores via MFMA (K=32, one MFMA per 16-col tile) ----
    const short8 av_s = *(const short8*)(x_attB + (size_t)(n0 + arow) * DH + q * 8);
#pragma unroll 4
    for (int i = 0; i < 16; ++i) {
        const int tl = w * 16 + i;
        const short8 bv = n_attP[tl * 64 + lane];
        floatx4 c = __builtin_amdgcn_mfma_f32_16x16x32_bf16(
            av_s, bv, (floatx4){0.f, 0.f, 0.f, 0.f}, 0, 0, 0);
        const int m = tl * 16 + nn;
#pragma unroll
        for (int u = 0; u < 2; ++u) {
            const int row = prow0 + u;
            const float sv = c[reg0 + u] * mask[(size_t)(n0 + row) * NROWS + m];
            pTr[row * PSTR + m] = f2bf(sv);
        }
    }
    __syncthreads();                               // barrier #1

    // ---- Phase 1b: softmax, wave w -> row w. Lane l owns elements
    //      jj*256 + 4l .. +3 : b64 bf16 reads (conflict-free), b32 fp8 writes
    //      (lane-linear, conflict-free). ----
    {
        const ushort_t* prow = pTr + w * PSTR;
        uchar_t* f8row = pF8 + w * PF8STR;
        uint2 raw[8];
        float mx = -1e30f;
#pragma unroll
        for (int jj = 0; jj < 8; ++jj) {
            raw[jj] = *(const uint2*)(prow + jj * 256 + 4 * lane);
            const float f0 = bf2f(raw[jj].x & 0xffffu), f1 = bf2f(raw[jj].x >> 16);
            const float f2 = bf2f(raw[jj].y & 0xffffu), f3 = bf2f(raw[jj].y >> 16);
            mx = fmaxf(mx, fmaxf(fmaxf(f0, f1), fmaxf(f2, f3)));
        }
#pragma unroll
        for (int off = 32; off >= 1; off >>= 1) mx = fmaxf(mx, __shfl_xor(mx, off));
        float sum = 0.f;
#pragma unroll
        for (int jj = 0; jj < 8; ++jj) {
            const float e0 = __expf(bf2f(raw[jj].x & 0xffffu) - mx);
            const float e1 = __expf(bf2f(raw[jj].x >> 16) - mx);
            const float e2 = __expf(bf2f(raw[jj].y & 0xffffu) - mx);
            const float e3 = __expf(bf2f(raw[jj].y >> 16) - mx);
            sum += (e0 + e1) + (e2 + e3);
            int p = 0;
            p = __builtin_amdgcn_cvt_pk_fp8_f32(e0, e1, p, false);
            p = __builtin_amdgcn_cvt_pk_fp8_f32(e2, e3, p, true);
            *(int*)(f8row + jj * 256 + 4 * lane) = p;
        }
#pragma unroll
        for (int off = 32; off >= 1; off >>= 1) sum += __shfl_xor(sum, off);
        if (lane == 0) row_inv[w] = 1.f / sum;
    }
    __syncthreads();                               // barrier #2

    // ---- Phase 2: PV (fp8). wave w: col tiles 2w, 2w+1; FULL K (64 slabs) ----
    const uchar_t* aBase = pF8 + arow * PF8STR;
    floatx4 accP[2][2];
#pragma unroll
    for (int tt = 0; tt < 2; ++tt)
#pragma unroll
        for (int pr = 0; pr < 2; ++pr) accP[tt][pr] = (floatx4){0.f, 0.f, 0.f, 0.f};

#pragma unroll 4
    for (int s = 0; s < 64; ++s) {
        const i64 av = *(const i64*)(aBase + s * 32 + q * 8);
        const int pr = s & 1;
#pragma unroll
        for (int tt = 0; tt < 2; ++tt) {
            const i64 bvv = B_pack8[(s * 16 + 2 * w + tt) * 64 + lane];
            accP[tt][pr] = __builtin_amdgcn_mfma_f32_16x16x32_fp8_fp8(
                av, bvv, accP[tt][pr], 0, 0, 0);
        }
    }
    // epilogue: sigmoid(acc * row_inv) -> ATr cols 256..511, all 64 lanes
#pragma unroll
    for (int tt = 0; tt < 2; ++tt) {
        const floatx4 a = accP[tt][0] + accP[tt][1];
        const int n = w * 32 + tt * 16 + nn;
#pragma unroll
        for (int u = 0; u < 2; ++u) {
            const int row = prow0 + u;
            ATr[row * ASTR + 256 + n] = f2bf(sigm(a[reg0 + u] * row_inv[row]));
        }
    }
    __syncthreads();                               // barrier #3

    // ---- Phase 3: FC (bf16). K=512 (16 slabs), wave w: col tiles 2w, 2w+1 ----
    const char* a2 = (const char*)ATr + arow * (ASTR * 2);
    floatx4 acc2[2][2];
#pragma unroll
    for (int tt = 0; tt < 2; ++tt)
#pragma unroll
        for (int pr = 0; pr < 2; ++pr) acc2[tt][pr] = (floatx4){0.f, 0.f, 0.f, 0.f};

#pragma unroll
    for (int s = 0; s < 16; ++s) {
        const short8 av = *(const short8*)(a2 + s * 64 + q * 16);
        const int pr = s & 1;
#pragma unroll
        for (int tt = 0; tt < 2; ++tt) {
            const short8 bv = W_pack[(s * 16 + 2 * w + tt) * 64 + lane];
            acc2[tt][pr] = __builtin_amdgcn_mfma_f32_16x16x32_bf16(av, bv, acc2[tt][pr], 0, 0, 0);
        }
    }
#pragma unroll
    for (int tt = 0; tt < 2; ++tt) {
        const floatx4 a = acc2[tt][0] + acc2[tt][1];
        const int n = w * 32 + tt * 16 + nn;
        const float bias = fcx_b[n];
#pragma unroll
        for (int u = 0; u < 2; ++u) {
            const int row = prow0 + u;
            out[(size_t)(n0 + row) * DOUT + n] = sigm(a[reg0 + u] + bias);
        }
    }
}

extern "C" void kernel_launch(void* const* d_in, const int* in_sizes, int n_in,
                              void* d_out, int out_size, void* d_ws, size_t ws_size,
                              hipStream_t stream) {
    const float* x      = (const float*)d_in[0];
    const float* neibs  = (const float*)d_in[1];
    // d_in[2] = edge_emb: dead code in the reference, intentionally unread.
    const float* mask   = (const float*)d_in[3];
    const float* ax_w1  = (const float*)d_in[4];
    const float* ax_b1  = (const float*)d_in[5];
    const float* ax_w2  = (const float*)d_in[6];
    const float* ax_b2  = (const float*)d_in[7];
    const float* an_w1  = (const float*)d_in[8];
    const float* an_b1  = (const float*)d_in[9];
    const float* an_w2  = (const float*)d_in[10];
    const float* an_b2  = (const float*)d_in[11];
    // d_in[12..15] = ae_* : dead code, unread.
    const float* fcx_w  = (const float*)d_in[16];
    const float* fcx_b  = (const float*)d_in[17];
    float* out = (float*)d_out;

    char* ws = (char*)d_ws;
    ushort_t* x_attB  = (ushort_t*)ws;                   // 128 KB
    short8*   n_attP  = (short8*)(ws + 131072);          // 128 KB
    i64*      B_pack8 = (i64*)(ws + 262144);             // 512 KB (fp8)
    short8*   W_pack  = (short8*)(ws + 786432);          // 256 KB

    prep_kernel<<<592, 256, 0, stream>>>(
        x, neibs, ax_w1, ax_b1, ax_w2, ax_b2,
        an_w1, an_b1, an_w2, an_b2, fcx_w,
        x_attB, n_attP, B_pack8, W_pack);

    attn_kernel<<<256, 512, 0, stream>>>(
        x, mask, x_attB, n_attP, B_pack8, W_pack, fcx_b, out);
}